// Round 6
// baseline (320.654 us; speedup 1.0000x reference)
//
#include <hip/hip_runtime.h>
#include <hip/hip_bf16.h>
#include <hip/hip_cooperative_groups.h>
#include <math.h>

namespace cg = cooperative_groups;

#define D 128
#define INV_TAU 5.0f

typedef short bf16x8 __attribute__((ext_vector_type(8)));
typedef unsigned short u16x8 __attribute__((ext_vector_type(8)));
typedef float f32x4 __attribute__((ext_vector_type(4)));

__device__ __forceinline__ unsigned short bf16_bits(float v) {
    __hip_bfloat16 hb = __float2bfloat16(v);
    return *(unsigned short*)&hb;
}

// ============================================================================
// Cooperative mega-kernel: all phases with grid.sync between.
// 512 blocks x 512 threads; LDS 53KB + VGPR<=128 => exactly 2 blocks/CU.
// ============================================================================
__global__ __launch_bounds__(512, 4) void mega_kernel(
    const float* __restrict__ emb, const int* __restrict__ pp,
    const int* __restrict__ stage, int* __restrict__ pos,
    unsigned short* __restrict__ hnn, float* __restrict__ hpn,
    float* __restrict__ s_out, unsigned short* __restrict__ sims,
    float* __restrict__ out, int N, int K, int q) {
    __shared__ unsigned short As[64 * 136];   // 17408 B
    __shared__ unsigned short Bs[128 * 136];  // 34816 B
    __shared__ int pos_s[64];
    __shared__ float redf[16];

    cg::grid_group grid = cg::this_grid();
    int tid = threadIdx.x;
    int wv = tid >> 6, lane = tid & 63;
    int quad = lane >> 4, l15 = lane & 15;

    // ---- P0: pos[a]=b scatter + zero output ----
    for (int k = blockIdx.x * 512 + tid; k < K; k += gridDim.x * 512)
        pos[pp[2 * k]] = pp[2 * k + 1];
    if (blockIdx.x == 0 && tid == 0) *out = 0.0f;
    grid.sync();

    // ---- P1: prep — partner (inline) + hard_neg bf16 + hard_pos fp32 ----
    {
        int g = tid >> 7, dd = tid & 127;  // 4 groups of 128 thr (2 waves each)
        int rowsPer = gridDim.x * 4;
        int total = N + K;
        int iters = (total + rowsPer - 1) / rowsPer;
        for (int it = 0; it < iters; ++it) {
            int r = it * rowsPer + blockIdx.x * 4 + g;
            bool act = r < total;
            bool isHn = act && (r < N);
            if (isHn && dd == 0) {
                int rr = r, posr = pos[rr];
                int jmax = -1;
                for (int j = N - 1; j >= 0; --j)
                    if (j != rr && j != posr) { jmax = j; break; }
                int imax = -1;
                for (int i = N - 1; i >= 0; --i)
                    if (i != rr && pos[i] != rr) { imax = i; break; }
                long long rowm = (jmax >= 0) ? (long long)rr * N + jmax : -1;
                long long colm = (imax >= 0) ? (long long)imax * N + rr : -1;
                pos_s[g] = (colm > rowm) ? (imax < 0 ? 0 : imax) : (jmax < 0 ? 0 : jmax);
            }
            __syncthreads();
            float h = 0.0f;
            int outrow = 0;
            if (act) {
                if (isHn) {
                    int p = pos_s[g];
                    h = 0.5f * (emb[r * D + dd] + emb[p * D + dd]);
                    outrow = r;
                } else {
                    int kk2 = r - N;
                    int a = pp[2 * kk2], bb = pp[2 * kk2 + 1];
                    h = 1.5f * emb[a * D + dd] - 0.5f * emb[bb * D + dd];
                    outrow = a;
                }
            }
            float ss = h * h;
#pragma unroll
            for (int off = 32; off > 0; off >>= 1) ss += __shfl_down(ss, off);
            if (lane == 0) redf[wv] = ss;
            __syncthreads();
            if (act) {
                float inv = 1.0f / fmaxf(sqrtf(redf[g * 2] + redf[g * 2 + 1]), 1e-8f);
                if (isHn)
                    hnn[(size_t)outrow * D + dd] = bf16_bits(h * inv);
                else
                    hpn[(size_t)outrow * D + dd] = h * inv;
            }
            __syncthreads();
        }
    }
    grid.sync();

    // ---- P2: 64x128-tile bf16 MFMA GEMM -> sortable-u16 sims ----
    {
        int nTilesCol = N >> 7;                    // 32
        int totalTiles = (N >> 6) * nTilesCol;     // 2048
        int rowg = wv >> 2, colg = wv & 3;         // 8 waves: 2 row x 4 col groups
        for (int t = blockIdx.x; t < totalTiles; t += gridDim.x) {
            int trow = t / nTilesCol, tcol = t - trow * nTilesCol;
            int rowBase = trow * 64, colBase = tcol * 128;
            __syncthreads();  // protect LDS from previous iteration's reads
            if (tid < 64) pos_s[tid] = pos[rowBase + tid];
#pragma unroll
            for (int i = 0; i < 2; ++i) {
                int idx = i * 512 + tid;
                int row = idx >> 4, seg = idx & 15;
                *(u16x8*)&As[row * 136 + seg * 8] =
                    *(const u16x8*)&hnn[(size_t)(rowBase + row) * D + seg * 8];
            }
#pragma unroll
            for (int i = 0; i < 4; ++i) {
                int idx = i * 512 + tid;
                int row = idx >> 4, seg = idx & 15;
                *(u16x8*)&Bs[row * 136 + seg * 8] =
                    *(const u16x8*)&hnn[(size_t)(colBase + row) * D + seg * 8];
            }
            __syncthreads();
            f32x4 acc[2][2] = {};
#pragma unroll
            for (int kk = 0; kk < 4; ++kk) {
                bf16x8 af[2], bf[2];
#pragma unroll
                for (int rt = 0; rt < 2; ++rt)
                    af[rt] = *(const bf16x8*)&As[(rowg * 32 + rt * 16 + l15) * 136 + kk * 32 + quad * 8];
#pragma unroll
                for (int ct = 0; ct < 2; ++ct)
                    bf[ct] = *(const bf16x8*)&Bs[(colg * 32 + ct * 16 + l15) * 136 + kk * 32 + quad * 8];
#pragma unroll
                for (int rt = 0; rt < 2; ++rt)
#pragma unroll
                    for (int ct = 0; ct < 2; ++ct)
                        acc[rt][ct] = __builtin_amdgcn_mfma_f32_16x16x32_bf16(
                            af[rt], bf[ct], acc[rt][ct], 0, 0, 0);
            }
#pragma unroll
            for (int rt = 0; rt < 2; ++rt) {
#pragma unroll
                for (int rg = 0; rg < 4; ++rg) {
                    int rloc = rowg * 32 + rt * 16 + quad * 4 + rg;
                    int r = rowBase + rloc;
                    int pr = pos_s[rloc];
#pragma unroll
                    for (int ct = 0; ct < 2; ++ct) {
                        int c = colBase + colg * 32 + ct * 16 + l15;
                        unsigned short u = bf16_bits(acc[rt][ct][rg]);
                        unsigned short sv = (u & 0x8000u) ? (unsigned short)~u
                                                          : (unsigned short)(u | 0x8000u);
                        if (c == r || c == pr) sv = 0x0080;  // sortable(-3.39e38): exp -> 0
                        sims[(size_t)r * N + c] = sv;
                    }
                }
            }
        }
    }
    grid.sync();

    // ---- P3: wave-per-row exact rank-select + exp-sum ----
    {
        int st = stage[0];
        int row = blockIdx.x * 8 + wv;
        if (row < N) {
            const unsigned short* rp = sims + (size_t)row * N;
            unsigned sarr[64];
#pragma unroll
            for (int j = 0; j < 8; ++j) {
                u16x8 tv = *(const u16x8*)&rp[j * 512 + lane * 8];
#pragma unroll
                for (int e = 0; e < 8; ++e) sarr[j * 8 + e] = (unsigned)(unsigned short)tv[e];
            }
            unsigned T = 0;
            if (st) {
#pragma unroll
                for (int b = 15; b >= 0; --b) {
                    unsigned cand = T | (1u << b);
                    int cnt = 0;
#pragma unroll
                    for (int i = 0; i < 64; ++i) cnt += (sarr[i] < cand);
#pragma unroll
                    for (int off = 1; off < 64; off <<= 1) cnt += __shfl_xor(cnt, off);
                    if (cnt <= q) T = cand;
                }
            }
            float sum = 0.0f;
#pragma unroll
            for (int i = 0; i < 64; ++i) {
                if (sarr[i] >= T) {
                    unsigned raw = (sarr[i] & 0x8000u) ? (sarr[i] ^ 0x8000u)
                                                       : (~sarr[i] & 0xFFFFu);
                    float f = __uint_as_float(raw << 16);
                    sum += __expf(f * INV_TAU);
                }
            }
#pragma unroll
            for (int off = 1; off < 64; off <<= 1) sum += __shfl_xor(sum, off);
            if (lane == 0) s_out[row] = sum;
        }
    }
    grid.sync();

    // ---- P4: per-pair loss + reduce ----
    {
        float part = 0.0f;
        int k = blockIdx.x * 8 + wv;
        if (k < K) {
            int a = pp[2 * k], b = pp[2 * k + 1];
            float dsum = hpn[a * D + lane] * hpn[b * D + lane] +
                         hpn[a * D + lane + 64] * hpn[b * D + lane + 64];
#pragma unroll
            for (int off = 32; off > 0; off >>= 1) dsum += __shfl_down(dsum, off);
            if (lane == 0) {
                float p = __expf(dsum * INV_TAU);
                part = log1pf(s_out[a] / p) + log1pf(s_out[b] / p);
            }
        }
        if (lane == 0) redf[wv] = part;
        __syncthreads();
        if (tid == 0) {
            float tot = 0.0f;
#pragma unroll
            for (int w = 0; w < 8; ++w) tot += redf[w];
            atomicAdd(out, tot / (2.0f * (float)K));
        }
    }
}

// ============================================================================
// Fallback path (R5 kernels, verbatim) — used if cooperative launch fails.
// ============================================================================
__global__ void scatter_pos_f(const int* __restrict__ pp, int* __restrict__ pos,
                              float* __restrict__ out, int K) {
    int k = blockIdx.x * blockDim.x + threadIdx.x;
    if (k == 0) *out = 0.0f;
    if (k < K) pos[pp[2 * k]] = pp[2 * k + 1];
}

__global__ void prep_kernel_f(const float* __restrict__ emb, const int* __restrict__ pos,
                              const int* __restrict__ pp, unsigned short* __restrict__ hnn,
                              float* __restrict__ hpn, int N) {
    int b = blockIdx.x, d = threadIdx.x;
    __shared__ int sP;
    __shared__ float tmp[2];
    bool isHn = (b < N);
    if (isHn && d == 0) {
        int r = b, posr = pos[r];
        int jmax = -1;
        for (int j = N - 1; j >= 0; --j)
            if (j != r && j != posr) { jmax = j; break; }
        int imax = -1;
        for (int i = N - 1; i >= 0; --i)
            if (i != r && pos[i] != r) { imax = i; break; }
        long long rowm = (jmax >= 0) ? (long long)r * N + jmax : -1;
        long long colm = (imax >= 0) ? (long long)imax * N + r : -1;
        sP = (colm > rowm) ? (imax < 0 ? 0 : imax) : (jmax < 0 ? 0 : jmax);
    }
    __syncthreads();
    float h;
    int outrow;
    if (isHn) {
        int p = sP;
        h = 0.5f * (emb[b * D + d] + emb[p * D + d]);
        outrow = b;
    } else {
        int k = b - N;
        int a = pp[2 * k], bb = pp[2 * k + 1];
        h = 1.5f * emb[a * D + d] - 0.5f * emb[bb * D + d];
        outrow = a;
    }
    float ss = h * h;
#pragma unroll
    for (int off = 32; off > 0; off >>= 1) ss += __shfl_down(ss, off);
    if ((d & 63) == 0) tmp[d >> 6] = ss;
    __syncthreads();
    float inv = 1.0f / fmaxf(sqrtf(tmp[0] + tmp[1]), 1e-8f);
    if (isHn)
        hnn[outrow * D + d] = bf16_bits(h * inv);
    else
        hpn[outrow * D + d] = h * inv;
}

__global__ __launch_bounds__(256) void gemm_sim_f(const unsigned short* __restrict__ hnn,
                                                  const int* __restrict__ pos,
                                                  unsigned short* __restrict__ sims, int N) {
    __shared__ unsigned short As[128 * 136];
    __shared__ unsigned short Bs[128 * 136];
    __shared__ int pos_s[128];
    int tid = threadIdx.x;
    int rowBase = blockIdx.y * 128, colBase = blockIdx.x * 128;
    if (tid < 128) pos_s[tid] = pos[rowBase + tid];
    u16x8 ra[8], rb[8];
#pragma unroll
    for (int i = 0; i < 8; ++i) {
        int idx = i * 256 + tid;
        int row = idx >> 4, seg = idx & 15;
        ra[i] = *(const u16x8*)&hnn[(size_t)(rowBase + row) * D + seg * 8];
        rb[i] = *(const u16x8*)&hnn[(size_t)(colBase + row) * D + seg * 8];
    }
#pragma unroll
    for (int i = 0; i < 8; ++i) {
        int idx = i * 256 + tid;
        int row = idx >> 4, seg = idx & 15;
        *(u16x8*)&As[row * 136 + seg * 8] = ra[i];
        *(u16x8*)&Bs[row * 136 + seg * 8] = rb[i];
    }
    __syncthreads();
    int wave = tid >> 6, lane = tid & 63;
    int quad = lane >> 4, l15 = lane & 15;
    int rowhalf = wave >> 1, colhalf = wave & 1;
    f32x4 acc[4][4] = {};
#pragma unroll
    for (int kk = 0; kk < 4; ++kk) {
        bf16x8 af[4], bf[4];
#pragma unroll
        for (int rt = 0; rt < 4; ++rt)
            af[rt] = *(const bf16x8*)&As[(rowhalf * 64 + rt * 16 + l15) * 136 + kk * 32 + quad * 8];
#pragma unroll
        for (int ct = 0; ct < 4; ++ct)
            bf[ct] = *(const bf16x8*)&Bs[(colhalf * 64 + ct * 16 + l15) * 136 + kk * 32 + quad * 8];
#pragma unroll
        for (int rt = 0; rt < 4; ++rt)
#pragma unroll
            for (int ct = 0; ct < 4; ++ct)
                acc[rt][ct] = __builtin_amdgcn_mfma_f32_16x16x32_bf16(af[rt], bf[ct],
                                                                     acc[rt][ct], 0, 0, 0);
    }
#pragma unroll
    for (int rt = 0; rt < 4; ++rt) {
#pragma unroll
        for (int rg = 0; rg < 4; ++rg) {
            int rloc = rowhalf * 64 + rt * 16 + quad * 4 + rg;
            int r = rowBase + rloc;
            int pr = pos_s[rloc];
#pragma unroll
            for (int ct = 0; ct < 4; ++ct) {
                int c = colBase + colhalf * 64 + ct * 16 + l15;
                unsigned short u = bf16_bits(acc[rt][ct][rg]);
                if (c == r || c == pr) u = 0xFF7F;
                sims[(size_t)r * N + c] = u;
            }
        }
    }
}

__global__ __launch_bounds__(512) void select_kernel_f(const unsigned short* __restrict__ sims,
                                                       const int* __restrict__ stage,
                                                       float* __restrict__ s_out, int N, int q) {
    int wave = threadIdx.x >> 6, lane = threadIdx.x & 63;
    int row = blockIdx.x * 8 + wave;
    const unsigned short* rp = sims + (size_t)row * N;
    unsigned s[64];
#pragma unroll
    for (int j = 0; j < 8; ++j) {
        u16x8 t = *(const u16x8*)&rp[j * 512 + lane * 8];
#pragma unroll
        for (int e = 0; e < 8; ++e) {
            unsigned u = (unsigned)(unsigned short)t[e];
            s[j * 8 + e] = (u & 0x8000u) ? (~u & 0xFFFFu) : (u | 0x8000u);
        }
    }
    unsigned T = 0;
    if (stage[0]) {
#pragma unroll
        for (int b = 15; b >= 0; --b) {
            unsigned cand = T | (1u << b);
            int cnt = 0;
#pragma unroll
            for (int i = 0; i < 64; ++i) cnt += (s[i] < cand);
#pragma unroll
            for (int off = 1; off < 64; off <<= 1) cnt += __shfl_xor(cnt, off);
            if (cnt <= q) T = cand;
        }
    }
    float sum = 0.0f;
#pragma unroll
    for (int i = 0; i < 64; ++i) {
        if (s[i] >= T) {
            unsigned u = (s[i] & 0x8000u) ? (s[i] ^ 0x8000u) : (~s[i] & 0xFFFFu);
            sum += __expf(__uint_as_float(u << 16) * INV_TAU);
        }
    }
#pragma unroll
    for (int off = 1; off < 64; off <<= 1) sum += __shfl_xor(sum, off);
    if (lane == 0) s_out[row] = sum;
}

__global__ __launch_bounds__(1024) void loss_kernel_f(const float* __restrict__ hpn,
                                                      const float* __restrict__ s,
                                                      const int* __restrict__ pp,
                                                      float* __restrict__ out, int K,
                                                      float scale) {
    int wave = threadIdx.x >> 6, lane = threadIdx.x & 63;
    int k = blockIdx.x * 16 + wave;
    float part = 0.0f;
    if (k < K) {
        int a = pp[2 * k], b = pp[2 * k + 1];
        float dsum = hpn[a * D + lane] * hpn[b * D + lane] +
                     hpn[a * D + lane + 64] * hpn[b * D + lane + 64];
#pragma unroll
        for (int off = 32; off > 0; off >>= 1) dsum += __shfl_down(dsum, off);
        if (lane == 0) {
            float p = __expf(dsum * INV_TAU);
            part = log1pf(s[a] / p) + log1pf(s[b] / p);
        }
    }
    __shared__ float red[16];
    if (lane == 0) red[wave] = part;
    __syncthreads();
    if (threadIdx.x == 0) {
        float tot = 0.0f;
#pragma unroll
        for (int w = 0; w < 16; ++w) tot += red[w];
        atomicAdd(out, tot * scale);
    }
}

extern "C" void kernel_launch(void* const* d_in, const int* in_sizes, int n_in,
                              void* d_out, int out_size, void* d_ws, size_t ws_size,
                              hipStream_t stream) {
    const float* emb = (const float*)d_in[0];
    const int* pp = (const int*)d_in[1];
    const int* stage = (const int*)d_in[2];
    int N = in_sizes[0] / D;  // 4096
    int K = in_sizes[1] / 2;  // 4096 pairs

    char* ws = (char*)d_ws;
    size_t offPos = 0;
    size_t offHnn = offPos + (size_t)N * 4;       // u16 N*D
    size_t offHpn = offHnn + (size_t)N * D * 2;   // fp32 N*D
    size_t offS = offHpn + (size_t)N * D * 4;     // fp32 N
    size_t offSims = offS + (size_t)N * 4;        // u16 N*N (32 MB)
    int* pos = (int*)(ws + offPos);
    unsigned short* hnn = (unsigned short*)(ws + offHnn);
    float* hpn = (float*)(ws + offHpn);
    float* s = (float*)(ws + offS);
    unsigned short* sims = (unsigned short*)(ws + offSims);
    float* out = (float*)d_out;
    int q = (int)(0.8 * (double)(N - 1));  // 3276 for N=4096

    void* args[] = {&emb, &pp, &stage, &pos, &hnn, &hpn, &s, &sims, &out, &N, &K, &q};
    hipError_t err = hipLaunchCooperativeKernel((const void*)mega_kernel, dim3(512),
                                                dim3(512), args, 0, stream);
    if (err != hipSuccess) {
        // fallback: 5-kernel pipeline (R5)
        scatter_pos_f<<<(K + 255) / 256, 256, 0, stream>>>(pp, pos, out, K);
        prep_kernel_f<<<N + K, D, 0, stream>>>(emb, pos, pp, hnn, hpn, N);
        dim3 g(N / 128, N / 128);
        gemm_sim_f<<<g, 256, 0, stream>>>(hnn, pos, sims, N);
        select_kernel_f<<<N / 8, 512, 0, stream>>>(sims, stage, s, N, q);
        loss_kernel_f<<<(K + 15) / 16, 1024, 0, stream>>>(hpn, s, pp, out, K,
                                                          1.0f / (2.0f * K));
    }
}

// Round 7
// 120.336 us; speedup vs baseline: 2.6647x; 2.6647x over previous
//
#include <hip/hip_runtime.h>
#include <hip/hip_bf16.h>
#include <math.h>

#define D 128
#define INV_TAU 5.0f

typedef short bf16x8 __attribute__((ext_vector_type(8)));
typedef unsigned short u16x8 __attribute__((ext_vector_type(8)));
typedef float f32x4 __attribute__((ext_vector_type(4)));

__device__ __forceinline__ unsigned short bf16_bits(float v) {
    __hip_bfloat16 hb = __float2bfloat16(v);
    return *(unsigned short*)&hb;
}

// ---------- K1: pos[a] = b for each pair; zero the output scalar ----------
__global__ void scatter_pos(const int* __restrict__ pp, int* __restrict__ pos,
                            float* __restrict__ out, int K) {
    int k = blockIdx.x * blockDim.x + threadIdx.x;
    if (k == 0) *out = 0.0f;
    if (k < K) pos[pp[2 * k]] = pp[2 * k + 1];
}

// ---------- K2: prep — blocks [0,N): partner (inline) + hard_neg norm -> bf16;
//                      blocks [N,N+K): hard_pos norm -> fp32 ----------
__global__ void prep_kernel(const float* __restrict__ emb, const int* __restrict__ pos,
                            const int* __restrict__ pp, unsigned short* __restrict__ hnn,
                            float* __restrict__ hpn, int N) {
    int b = blockIdx.x, d = threadIdx.x;  // blockDim = 128
    __shared__ int sP;
    __shared__ float tmp[2];
    bool isHn = (b < N);
    if (isHn && d == 0) {
        int r = b, posr = pos[r];
        int jmax = -1;
        for (int j = N - 1; j >= 0; --j)
            if (j != r && j != posr) { jmax = j; break; }
        int imax = -1;
        for (int i = N - 1; i >= 0; --i)
            if (i != r && pos[i] != r) { imax = i; break; }
        long long rowm = (jmax >= 0) ? (long long)r * N + jmax : -1;
        long long colm = (imax >= 0) ? (long long)imax * N + r : -1;
        sP = (colm > rowm) ? (imax < 0 ? 0 : imax) : (jmax < 0 ? 0 : jmax);
    }
    __syncthreads();
    float h;
    int outrow;
    if (isHn) {
        int p = sP;
        h = 0.5f * (emb[b * D + d] + emb[p * D + d]);
        outrow = b;
    } else {
        int k = b - N;
        int a = pp[2 * k], bb = pp[2 * k + 1];
        h = 1.5f * emb[a * D + d] - 0.5f * emb[bb * D + d];
        outrow = a;
    }
    float ss = h * h;
#pragma unroll
    for (int off = 32; off > 0; off >>= 1) ss += __shfl_down(ss, off);
    if ((d & 63) == 0) tmp[d >> 6] = ss;
    __syncthreads();
    float inv = 1.0f / fmaxf(sqrtf(tmp[0] + tmp[1]), 1e-8f);
    if (isHn)
        hnn[outrow * D + d] = bf16_bits(h * inv);
    else
        hpn[outrow * D + d] = h * inv;
}

// ---------- K3: 128x128-tile bf16 MFMA GEMM -> sortable-u16 sims ----------
// 256 thr = 4 waves; wave (rowhalf, colhalf) computes a 64x64 quadrant.
// LDS row stride 136 u16: frag ds_read_b128 <=2-way conflicts (free, m136).
// Epilogue: C-tile staged in As (LDS transpose) -> fully-coalesced dwordx4 stores.
__global__ __launch_bounds__(256) void gemm_sim(const unsigned short* __restrict__ hnn,
                                                const int* __restrict__ pos,
                                                unsigned short* __restrict__ sims, int N) {
    __shared__ unsigned short As[128 * 136];
    __shared__ unsigned short Bs[128 * 136];
    __shared__ int pos_s[128];
    int tid = threadIdx.x;
    int rowBase = blockIdx.y * 128, colBase = blockIdx.x * 128;
    if (tid < 128) pos_s[tid] = pos[rowBase + tid];

    u16x8 ra[8], rb[8];
#pragma unroll
    for (int i = 0; i < 8; ++i) {
        int idx = i * 256 + tid;
        int row = idx >> 4, seg = idx & 15;
        ra[i] = *(const u16x8*)&hnn[(size_t)(rowBase + row) * D + seg * 8];
        rb[i] = *(const u16x8*)&hnn[(size_t)(colBase + row) * D + seg * 8];
    }
#pragma unroll
    for (int i = 0; i < 8; ++i) {
        int idx = i * 256 + tid;
        int row = idx >> 4, seg = idx & 15;
        *(u16x8*)&As[row * 136 + seg * 8] = ra[i];
        *(u16x8*)&Bs[row * 136 + seg * 8] = rb[i];
    }
    __syncthreads();

    int wave = tid >> 6, lane = tid & 63;
    int quad = lane >> 4, l15 = lane & 15;
    int rowhalf = wave >> 1, colhalf = wave & 1;

    f32x4 acc[4][4] = {};
#pragma unroll
    for (int kk = 0; kk < 4; ++kk) {
        bf16x8 af[4], bf[4];
#pragma unroll
        for (int rt = 0; rt < 4; ++rt)
            af[rt] = *(const bf16x8*)&As[(rowhalf * 64 + rt * 16 + l15) * 136 + kk * 32 + quad * 8];
#pragma unroll
        for (int ct = 0; ct < 4; ++ct)
            bf[ct] = *(const bf16x8*)&Bs[(colhalf * 64 + ct * 16 + l15) * 136 + kk * 32 + quad * 8];
#pragma unroll
        for (int rt = 0; rt < 4; ++rt)
#pragma unroll
            for (int ct = 0; ct < 4; ++ct)
                acc[rt][ct] = __builtin_amdgcn_mfma_f32_16x16x32_bf16(af[rt], bf[ct],
                                                                     acc[rt][ct], 0, 0, 0);
    }
    __syncthreads();  // done reading As/Bs; reuse As as the C-tile

    // stage masked sortable-u16 into LDS (2-way bank aliasing only)
#pragma unroll
    for (int rt = 0; rt < 4; ++rt) {
#pragma unroll
        for (int rg = 0; rg < 4; ++rg) {
            int rloc = rowhalf * 64 + rt * 16 + quad * 4 + rg;
            int r = rowBase + rloc;
            int pr = pos_s[rloc];
#pragma unroll
            for (int ct = 0; ct < 4; ++ct) {
                int cloc = colhalf * 64 + ct * 16 + l15;
                int c = colBase + cloc;
                unsigned short u = bf16_bits(acc[rt][ct][rg]);
                unsigned short sv = (u & 0x8000u) ? (unsigned short)~u
                                                  : (unsigned short)(u | 0x8000u);
                if (c == r || c == pr) sv = 0x0080;  // sortable(-3.39e38) -> exp == 0
                As[rloc * 136 + cloc] = sv;
            }
        }
    }
    __syncthreads();

    // coalesced write-out: 8 x dwordx4 per thread (1 KB per wave-instr)
#pragma unroll
    for (int i = 0; i < 8; ++i) {
        int idx = i * 256 + tid;
        int row = idx >> 4, seg = idx & 15;
        *(u16x8*)&sims[(size_t)(rowBase + row) * N + colBase + seg * 8] =
            *(const u16x8*)&As[row * 136 + seg * 8];
    }
}

// ---------- K4: wave-per-row exact rank-select + exp-sum (register-resident) ----------
// 512 thr = 8 waves = 8 rows per block; sims already sortable-u16.
// Exact rank q via 16-step bitwise binary search (cmp + wave-reduce, no LDS).
__global__ __launch_bounds__(512) void select_kernel(const unsigned short* __restrict__ sims,
                                                     const int* __restrict__ stage,
                                                     float* __restrict__ s_out, int N, int q) {
    int wave = threadIdx.x >> 6, lane = threadIdx.x & 63;
    int row = blockIdx.x * 8 + wave;
    const unsigned short* rp = sims + (size_t)row * N;

    unsigned s[64];
#pragma unroll
    for (int j = 0; j < 8; ++j) {
        u16x8 t = *(const u16x8*)&rp[j * 512 + lane * 8];
#pragma unroll
        for (int e = 0; e < 8; ++e) s[j * 8 + e] = (unsigned)(unsigned short)t[e];
    }

    unsigned T = 0;
    if (stage[0]) {
#pragma unroll
        for (int b = 15; b >= 0; --b) {
            unsigned cand = T | (1u << b);
            int cnt = 0;
#pragma unroll
            for (int i = 0; i < 64; ++i) cnt += (s[i] < cand);
#pragma unroll
            for (int off = 1; off < 64; off <<= 1) cnt += __shfl_xor(cnt, off);
            if (cnt <= q) T = cand;  // rank-q element is >= cand
        }
    }

    float sum = 0.0f;
#pragma unroll
    for (int i = 0; i < 64; ++i) {
        if (s[i] >= T) {
            unsigned raw = (s[i] & 0x8000u) ? (s[i] ^ 0x8000u) : (~s[i] & 0xFFFFu);
            sum += __expf(__uint_as_float(raw << 16) * INV_TAU);
        }
    }
#pragma unroll
    for (int off = 1; off < 64; off <<= 1) sum += __shfl_xor(sum, off);
    if (lane == 0) s_out[row] = sum;
}

// ---------- K5: per-pair positive cos + two-level loss reduction ----------
__global__ __launch_bounds__(1024) void loss_kernel(const float* __restrict__ hpn,
                                                    const float* __restrict__ s,
                                                    const int* __restrict__ pp,
                                                    float* __restrict__ out, int K,
                                                    float scale) {
    int wave = threadIdx.x >> 6, lane = threadIdx.x & 63;
    int k = blockIdx.x * 16 + wave;
    float part = 0.0f;
    if (k < K) {
        int a = pp[2 * k], b = pp[2 * k + 1];
        float dsum = hpn[a * D + lane] * hpn[b * D + lane] +
                     hpn[a * D + lane + 64] * hpn[b * D + lane + 64];
#pragma unroll
        for (int off = 32; off > 0; off >>= 1) dsum += __shfl_down(dsum, off);
        if (lane == 0) {
            float p = __expf(dsum * INV_TAU);
            part = log1pf(s[a] / p) + log1pf(s[b] / p);
        }
    }
    __shared__ float red[16];
    if (lane == 0) red[wave] = part;
    __syncthreads();
    if (threadIdx.x == 0) {
        float tot = 0.0f;
#pragma unroll
        for (int w = 0; w < 16; ++w) tot += red[w];
        atomicAdd(out, tot * scale);
    }
}

extern "C" void kernel_launch(void* const* d_in, const int* in_sizes, int n_in,
                              void* d_out, int out_size, void* d_ws, size_t ws_size,
                              hipStream_t stream) {
    const float* emb = (const float*)d_in[0];
    const int* pp = (const int*)d_in[1];
    const int* stage = (const int*)d_in[2];
    int N = in_sizes[0] / D;  // 4096
    int K = in_sizes[1] / 2;  // 4096 pairs

    char* ws = (char*)d_ws;
    size_t offPos = 0;
    size_t offHnn = offPos + (size_t)N * 4;       // u16 N*D
    size_t offHpn = offHnn + (size_t)N * D * 2;   // fp32 N*D
    size_t offS = offHpn + (size_t)N * D * 4;     // fp32 N
    size_t offSims = offS + (size_t)N * 4;        // u16 N*N (32 MB)
    int* pos = (int*)(ws + offPos);
    unsigned short* hnn = (unsigned short*)(ws + offHnn);
    float* hpn = (float*)(ws + offHpn);
    float* s = (float*)(ws + offS);
    unsigned short* sims = (unsigned short*)(ws + offSims);

    scatter_pos<<<(K + 255) / 256, 256, 0, stream>>>(pp, pos, (float*)d_out, K);
    prep_kernel<<<N + K, D, 0, stream>>>(emb, pos, pp, hnn, hpn, N);
    dim3 g(N / 128, N / 128);
    gemm_sim<<<g, 256, 0, stream>>>(hnn, pos, sims, N);
    int q = (int)(0.8 * (double)(N - 1));  // 3276 for N=4096
    select_kernel<<<N / 8, 512, 0, stream>>>(sims, stage, s, N, q);
    loss_kernel<<<(K + 15) / 16, 1024, 0, stream>>>(hpn, s, pp, (float*)d_out, K,
                                                    1.0f / (2.0f * K));
}